// Round 1
// baseline (234.945 us; speedup 1.0000x reference)
//
#include <hip/hip_runtime.h>

#define BB 8192
#define TT 50
#define II 50
#define HH 10
#define CC 5

__device__ __forceinline__ float fast_tanh(float x) {
    float e = __expf(2.0f * x);
    return 1.0f - 2.0f * __builtin_amdgcn_rcpf(e + 1.0f);
}

// K1: P[t][j][b] = sum_i x[b][t][i] * Wih0[j][i] + (bih0[j]+bhh0[j])
__global__ __launch_bounds__(256) void k_proj0(
    const float* __restrict__ x, const float* __restrict__ Wih0,
    const float* __restrict__ bih0, const float* __restrict__ bhh0,
    float* __restrict__ P) {
    int gid = blockIdx.x * 256 + threadIdx.x;   // 0 .. B*T-1
    int b = gid & (BB - 1);
    int t = gid >> 13;                          // B = 2^13
    const float* xr = x + ((size_t)b * TT + t) * II;
    float xv[II];
#pragma unroll
    for (int i = 0; i < II; i++) xv[i] = xr[i];
#pragma unroll
    for (int j = 0; j < HH; j++) {
        float a = bih0[j] + bhh0[j];
        const float* w = Wih0 + j * II;
#pragma unroll
        for (int i = 0; i < II; i++) a = fmaf(w[i], xv[i], a);
        P[((size_t)t * HH + j) * BB + b] = a;
    }
}

// K2/K3: layer-l recurrence + layer-(l+1) input projection, in place on P.
// h_t = tanh(P[t] + Whh h_{t-1});  P[t] <- (bi+bh) + Wnext h_t
__global__ __launch_bounds__(64) void k_rec_proj(
    const float* __restrict__ hinit, const float* __restrict__ Whh,
    const float* __restrict__ Wnext, const float* __restrict__ bi,
    const float* __restrict__ bh, float* __restrict__ P) {
    int b = blockIdx.x * 64 + threadIdx.x;
    float h[HH], whh[HH * HH], wnx[HH * HH], bias[HH], p[HH];
#pragma unroll
    for (int j = 0; j < HH; j++) h[j] = hinit[(size_t)b * HH + j];
#pragma unroll
    for (int k = 0; k < HH * HH; k++) { whh[k] = Whh[k]; wnx[k] = Wnext[k]; }
#pragma unroll
    for (int j = 0; j < HH; j++) bias[j] = bi[j] + bh[j];
#pragma unroll
    for (int j = 0; j < HH; j++) p[j] = P[(size_t)j * BB + b];

    for (int t = 0; t < TT; t++) {
        float pn[HH];
        if (t + 1 < TT) {
#pragma unroll
            for (int j = 0; j < HH; j++) pn[j] = P[((size_t)(t + 1) * HH + j) * BB + b];
        }
        float hn[HH];
#pragma unroll
        for (int j = 0; j < HH; j++) {
            float a = p[j];
#pragma unroll
            for (int k = 0; k < HH; k++) a = fmaf(whh[j * HH + k], h[k], a);
            hn[j] = fast_tanh(a);
        }
#pragma unroll
        for (int j = 0; j < HH; j++) h[j] = hn[j];
#pragma unroll
        for (int j = 0; j < HH; j++) {
            float a = bias[j];
#pragma unroll
            for (int k = 0; k < HH; k++) a = fmaf(wnx[j * HH + k], h[k], a);
            P[((size_t)t * HH + j) * BB + b] = a;
        }
#pragma unroll
        for (int j = 0; j < HH; j++) p[j] = pn[j];
    }
}

// K4: layer-2 recurrence + ReLU + FC accumulation.
__global__ __launch_bounds__(64) void k_rec_fc(
    const float* __restrict__ hinit, const float* __restrict__ Whh,
    const float* __restrict__ fcw, const float* __restrict__ fcb,
    const float* __restrict__ P, float* __restrict__ out) {
    int b = blockIdx.x * 64 + threadIdx.x;
    float h[HH], whh[HH * HH], acc[CC], p[HH];
#pragma unroll
    for (int j = 0; j < HH; j++) h[j] = hinit[(size_t)b * HH + j];
#pragma unroll
    for (int k = 0; k < HH * HH; k++) whh[k] = Whh[k];
#pragma unroll
    for (int c = 0; c < CC; c++) acc[c] = fcb[c];
#pragma unroll
    for (int j = 0; j < HH; j++) p[j] = P[(size_t)j * BB + b];

    for (int t = 0; t < TT; t++) {
        float pn[HH];
        if (t + 1 < TT) {
#pragma unroll
            for (int j = 0; j < HH; j++) pn[j] = P[((size_t)(t + 1) * HH + j) * BB + b];
        }
        float hn[HH], r[HH];
#pragma unroll
        for (int j = 0; j < HH; j++) {
            float a = p[j];
#pragma unroll
            for (int k = 0; k < HH; k++) a = fmaf(whh[j * HH + k], h[k], a);
            hn[j] = fast_tanh(a);
        }
#pragma unroll
        for (int j = 0; j < HH; j++) { h[j] = hn[j]; r[j] = fmaxf(hn[j], 0.0f); }
#pragma unroll
        for (int c = 0; c < CC; c++) {
            const float* w = fcw + (size_t)c * (TT * HH) + t * HH;
#pragma unroll
            for (int j = 0; j < HH; j++) acc[c] = fmaf(w[j], r[j], acc[c]);
        }
#pragma unroll
        for (int j = 0; j < HH; j++) p[j] = pn[j];
    }
#pragma unroll
    for (int c = 0; c < CC; c++) out[(size_t)b * CC + c] = acc[c];
}

extern "C" void kernel_launch(void* const* d_in, const int* in_sizes, int n_in,
                              void* d_out, int out_size, void* d_ws, size_t ws_size,
                              hipStream_t stream) {
    const float* x    = (const float*)d_in[0];
    const float* h0   = (const float*)d_in[1];
    const float* Wih0 = (const float*)d_in[2];
    const float* Whh0 = (const float*)d_in[3];
    const float* bih0 = (const float*)d_in[4];
    const float* bhh0 = (const float*)d_in[5];
    const float* Wih1 = (const float*)d_in[6];
    const float* Whh1 = (const float*)d_in[7];
    const float* bih1 = (const float*)d_in[8];
    const float* bhh1 = (const float*)d_in[9];
    const float* Wih2 = (const float*)d_in[10];
    const float* Whh2 = (const float*)d_in[11];
    const float* bih2 = (const float*)d_in[12];
    const float* bhh2 = (const float*)d_in[13];
    const float* fcw  = (const float*)d_in[14];
    const float* fcb  = (const float*)d_in[15];
    float* out = (float*)d_out;
    float* P   = (float*)d_ws;   // [T][H][B] = 16.38 MB

    k_proj0<<<(BB * TT) / 256, 256, 0, stream>>>(x, Wih0, bih0, bhh0, P);
    k_rec_proj<<<BB / 64, 64, 0, stream>>>(h0 + (size_t)0 * BB * HH, Whh0, Wih1, bih1, bhh1, P);
    k_rec_proj<<<BB / 64, 64, 0, stream>>>(h0 + (size_t)1 * BB * HH, Whh1, Wih2, bih2, bhh2, P);
    k_rec_fc<<<BB / 64, 64, 0, stream>>>(h0 + (size_t)2 * BB * HH, Whh2, fcw, fcb, P, out);
}

// Round 2
// 98.521 us; speedup vs baseline: 2.3847x; 2.3847x over previous
//
#include <hip/hip_runtime.h>

#define BB 8192
#define TT 50
#define II 50
#define HH 10
#define HF 5
#define CC 5

__device__ __forceinline__ float fast_tanh(float x) {
    float e = __expf(2.0f * x);
    return 1.0f - 2.0f * __builtin_amdgcn_rcpf(e + 1.0f);
}

// K1: P[t][j][b] = sum_i x[b][t][i] * Wih0[j][i] + (bih0[j]+bhh0[j])
__global__ __launch_bounds__(256) void k_proj0(
    const float* __restrict__ x, const float* __restrict__ Wih0,
    const float* __restrict__ bih0, const float* __restrict__ bhh0,
    float* __restrict__ P) {
    int gid = blockIdx.x * 256 + threadIdx.x;   // 0 .. B*T-1
    int b = gid & (BB - 1);
    int t = gid >> 13;                          // B = 2^13
    const float2* xr = (const float2*)(x + ((size_t)b * TT + t) * II);
    float2 xv[II / 2];
#pragma unroll
    for (int i = 0; i < II / 2; i++) xv[i] = xr[i];
#pragma unroll
    for (int j = 0; j < HH; j++) {
        float a = bih0[j] + bhh0[j];
        const float2* w = (const float2*)(Wih0 + j * II);
#pragma unroll
        for (int i = 0; i < II / 2; i++) {
            float2 wv = w[i];
            a = fmaf(wv.x, xv[i].x, a);
            a = fmaf(wv.y, xv[i].y, a);
        }
        P[((size_t)t * HH + j) * BB + b] = a;
    }
}

// K2: fused 3-layer recurrence + FC. 2 threads per batch (row-split by 5).
// Lanes 0-31: p=0 (rows 0-4) for 32 batches; lanes 32-63: p=1 (rows 5-9), same batches.
__global__ __launch_bounds__(64, 1) void k_fused(
    const float* __restrict__ h0all,
    const float* __restrict__ Whh0,
    const float* __restrict__ Wih1, const float* __restrict__ Whh1,
    const float* __restrict__ bih1, const float* __restrict__ bhh1,
    const float* __restrict__ Wih2, const float* __restrict__ Whh2,
    const float* __restrict__ bih2, const float* __restrict__ bhh2,
    const float* __restrict__ fcw, const float* __restrict__ fcb,
    const float* __restrict__ P, float* __restrict__ out) {
    __shared__ __align__(16) float sfc[TT * CC * 16];  // packed fcw, 16 KB

    int tid = threadIdx.x;
    // stage fcw into LDS, packed: (t,c,j) -> sfc[(t*5+c)*16 + (j<5 ? j : j+3)]
    for (int i = tid; i < TT * CC * HH; i += 64) {
        int t = i / (CC * HH);
        int r = i - t * (CC * HH);
        int c = r / HH;
        int j = r - c * HH;
        sfc[(t * CC + c) * 16 + (j < 5 ? j : j + 3)] = fcw[(size_t)c * (TT * HH) + t * HH + j];
    }

    int p = tid >> 5;               // 0 or 1 (row-half)
    int b = blockIdx.x * 32 + (tid & 31);
    int jbase = p * HF;

    // per-thread weight halves (rows jbase..jbase+4)
    float w0[HF][HH], wi1[HF][HH], w1[HF][HH], wi2[HF][HH], w2[HF][HH];
    float bs1[HF], bs2[HF];
#pragma unroll
    for (int jj = 0; jj < HF; jj++) {
        int j = jbase + jj;
#pragma unroll
        for (int k = 0; k < HH; k++) {
            w0[jj][k]  = Whh0[j * HH + k];
            wi1[jj][k] = Wih1[j * HH + k];
            w1[jj][k]  = Whh1[j * HH + k];
            wi2[jj][k] = Wih2[j * HH + k];
            w2[jj][k]  = Whh2[j * HH + k];
        }
        bs1[jj] = bih1[j] + bhh1[j];
        bs2[jj] = bih2[j] + bhh2[j];
    }

    float h0[HH], h1[HH], h2[HH];
#pragma unroll
    for (int k = 0; k < HH; k++) {
        h0[k] = h0all[(size_t)0 * BB * HH + (size_t)b * HH + k];
        h1[k] = h0all[(size_t)1 * BB * HH + (size_t)b * HH + k];
        h2[k] = h0all[(size_t)2 * BB * HH + (size_t)b * HH + k];
    }

    float acc[CC];
#pragma unroll
    for (int c = 0; c < CC; c++) acc[c] = 0.0f;

    float pc[HF];
#pragma unroll
    for (int jj = 0; jj < HF; jj++) pc[jj] = P[((size_t)0 * HH + jbase + jj) * BB + b];

    __syncthreads();

#pragma unroll 1
    for (int t = 0; t < TT; t++) {
        float pn[HF];
        if (t + 1 < TT) {
#pragma unroll
            for (int jj = 0; jj < HF; jj++)
                pn[jj] = P[((size_t)(t + 1) * HH + jbase + jj) * BB + b];
        }
        float mine[HF], theirs[HF];
        // ---- layer 0 ----
#pragma unroll
        for (int jj = 0; jj < HF; jj++) {
            float a = pc[jj];
#pragma unroll
            for (int k = 0; k < HH; k++) a = fmaf(w0[jj][k], h0[k], a);
            mine[jj] = fast_tanh(a);
        }
#pragma unroll
        for (int jj = 0; jj < HF; jj++) theirs[jj] = __shfl_xor(mine[jj], 32, 64);
#pragma unroll
        for (int k = 0; k < HF; k++) {
            h0[k]      = p ? theirs[k] : mine[k];
            h0[HF + k] = p ? mine[k] : theirs[k];
        }
        // ---- layer 1 ----
#pragma unroll
        for (int jj = 0; jj < HF; jj++) {
            float a = bs1[jj];
#pragma unroll
            for (int k = 0; k < HH; k++) a = fmaf(wi1[jj][k], h0[k], a);
#pragma unroll
            for (int k = 0; k < HH; k++) a = fmaf(w1[jj][k], h1[k], a);
            mine[jj] = fast_tanh(a);
        }
#pragma unroll
        for (int jj = 0; jj < HF; jj++) theirs[jj] = __shfl_xor(mine[jj], 32, 64);
#pragma unroll
        for (int k = 0; k < HF; k++) {
            h1[k]      = p ? theirs[k] : mine[k];
            h1[HF + k] = p ? mine[k] : theirs[k];
        }
        // ---- layer 2 ----
#pragma unroll
        for (int jj = 0; jj < HF; jj++) {
            float a = bs2[jj];
#pragma unroll
            for (int k = 0; k < HH; k++) a = fmaf(wi2[jj][k], h1[k], a);
#pragma unroll
            for (int k = 0; k < HH; k++) a = fmaf(w2[jj][k], h2[k], a);
            mine[jj] = fast_tanh(a);
        }
#pragma unroll
        for (int jj = 0; jj < HF; jj++) theirs[jj] = __shfl_xor(mine[jj], 32, 64);
#pragma unroll
        for (int k = 0; k < HF; k++) {
            h2[k]      = p ? theirs[k] : mine[k];
            h2[HF + k] = p ? mine[k] : theirs[k];
        }
        // ---- FC partial on own rows (mine == fresh h2 rows jbase..jbase+4) ----
        float r[HF];
#pragma unroll
        for (int jj = 0; jj < HF; jj++) r[jj] = fmaxf(mine[jj], 0.0f);
#pragma unroll
        for (int c = 0; c < CC; c++) {
            const float* base = &sfc[(t * CC + c) * 16 + p * 8];
            float4 f4 = *(const float4*)base;
            float f1 = base[4];
            acc[c] = fmaf(f4.x, r[0], acc[c]);
            acc[c] = fmaf(f4.y, r[1], acc[c]);
            acc[c] = fmaf(f4.z, r[2], acc[c]);
            acc[c] = fmaf(f4.w, r[3], acc[c]);
            acc[c] = fmaf(f1,  r[4], acc[c]);
        }
#pragma unroll
        for (int jj = 0; jj < HF; jj++) pc[jj] = pn[jj];
    }

    float o[CC];
#pragma unroll
    for (int c = 0; c < CC; c++) o[c] = acc[c] + __shfl_xor(acc[c], 32, 64) + fcb[c];
    if (p == 0) {
#pragma unroll
        for (int c = 0; c < CC; c++) out[(size_t)b * CC + c] = o[c];
    }
}

extern "C" void kernel_launch(void* const* d_in, const int* in_sizes, int n_in,
                              void* d_out, int out_size, void* d_ws, size_t ws_size,
                              hipStream_t stream) {
    const float* x    = (const float*)d_in[0];
    const float* h0   = (const float*)d_in[1];
    const float* Wih0 = (const float*)d_in[2];
    const float* Whh0 = (const float*)d_in[3];
    const float* bih0 = (const float*)d_in[4];
    const float* bhh0 = (const float*)d_in[5];
    const float* Wih1 = (const float*)d_in[6];
    const float* Whh1 = (const float*)d_in[7];
    const float* bih1 = (const float*)d_in[8];
    const float* bhh1 = (const float*)d_in[9];
    const float* Wih2 = (const float*)d_in[10];
    const float* Whh2 = (const float*)d_in[11];
    const float* bih2 = (const float*)d_in[12];
    const float* bhh2 = (const float*)d_in[13];
    const float* fcw  = (const float*)d_in[14];
    const float* fcb  = (const float*)d_in[15];
    float* out = (float*)d_out;
    float* P   = (float*)d_ws;   // [T][H][B] = 16.38 MB

    k_proj0<<<(BB * TT) / 256, 256, 0, stream>>>(x, Wih0, bih0, bhh0, P);
    k_fused<<<BB / 32, 64, 0, stream>>>(h0, Whh0, Wih1, Whh1, bih1, bhh1,
                                        Wih2, Whh2, bih2, bhh2, fcw, fcb, P, out);
}

// Round 4
// 87.485 us; speedup vs baseline: 2.6856x; 1.1262x over previous
//
#include <hip/hip_runtime.h>

#define BB 8192
#define TT 50
#define II 50
#define HH 10
#define HF 5
#define CC 5

__device__ __forceinline__ float fast_tanh(float x) {
    float e = __expf(2.0f * x);
    return 1.0f - 2.0f * __builtin_amdgcn_rcpf(e + 1.0f);
}

// After calling with u=v=x: {u,v} = {x[lane&~16], x[lane|16]} (order HW-defined).
__device__ __forceinline__ void swap16(float& u, float& v) {
#if __has_builtin(__builtin_amdgcn_permlane16_swap)
    auto r = __builtin_amdgcn_permlane16_swap(__float_as_uint(u), __float_as_uint(v), false, false);
    u = __uint_as_float(r[0]);
    v = __uint_as_float(r[1]);
#else
    asm("s_nop 1\n\tv_permlane16_swap_b32 %0, %1\n\ts_nop 0" : "+v"(u), "+v"(v));
#endif
}
// After calling with u=v=x: {u,v} = {x[lane&~32], x[lane|32]} (order HW-defined).
__device__ __forceinline__ void swap32(float& u, float& v) {
#if __has_builtin(__builtin_amdgcn_permlane32_swap)
    auto r = __builtin_amdgcn_permlane32_swap(__float_as_uint(u), __float_as_uint(v), false, false);
    u = __uint_as_float(r[0]);
    v = __uint_as_float(r[1]);
#else
    asm("s_nop 1\n\tv_permlane32_swap_b32 %0, %1\n\ts_nop 0" : "+v"(u), "+v"(v));
#endif
}

// K1: P[t][j][b] = sum_i x[b][t][i] * Wih0[j][i] + (bih0[j]+bhh0[j])
__global__ __launch_bounds__(256) void k_proj0(
    const float* __restrict__ x, const float* __restrict__ Wih0,
    const float* __restrict__ bih0, const float* __restrict__ bhh0,
    float* __restrict__ P) {
    int gid = blockIdx.x * 256 + threadIdx.x;   // 0 .. B*T-1
    int b = gid & (BB - 1);
    int t = gid >> 13;                          // B = 2^13
    const float2* xr = (const float2*)(x + ((size_t)b * TT + t) * II);
    float2 xv[II / 2];
#pragma unroll
    for (int i = 0; i < II / 2; i++) xv[i] = xr[i];
#pragma unroll
    for (int j = 0; j < HH; j++) {
        float a = bih0[j] + bhh0[j];
        const float2* w = (const float2*)(Wih0 + j * II);
#pragma unroll
        for (int i = 0; i < II / 2; i++) {
            float2 wv = w[i];
            a = fmaf(wv.x, xv[i].x, a);
            a = fmaf(wv.y, xv[i].y, a);
        }
        P[((size_t)t * HH + j) * BB + b] = a;
    }
}

// K2: fused 3-layer recurrence + FC.
// 4 threads per batch: lane = p*32 + q*16 + bidx (16 batches/wave).
// p = row-half (rows p*5..p*5+4), q = k-half of every dot product.
// q-reduce: swap16 + add (commutative, orientation-immune).
// p-exchange: swap32 gives {own, partner} as a set; partner = (u+v) - own.
__global__ __launch_bounds__(64, 1) void k_fused(
    const float* __restrict__ h0all,
    const float* __restrict__ Whh0,
    const float* __restrict__ Wih1, const float* __restrict__ Whh1,
    const float* __restrict__ bih1, const float* __restrict__ bhh1,
    const float* __restrict__ Wih2, const float* __restrict__ Whh2,
    const float* __restrict__ bih2, const float* __restrict__ bhh2,
    const float* __restrict__ fcw, const float* __restrict__ fcb,
    const float* __restrict__ P, float* __restrict__ out) {
    __shared__ __align__(16) float sfc[TT * CC * 16];  // packed fcw, 16 KB

    int tid = threadIdx.x;
    // stage fcw into LDS: (t,c,j) -> sfc[(t*5+c)*16 + (j<5 ? j : j+3)]
    for (int i = tid; i < TT * CC * HH; i += 64) {
        int t = i / (CC * HH);
        int r = i - t * (CC * HH);
        int c = r / HH;
        int j = r - c * HH;
        sfc[(t * CC + c) * 16 + (j < 5 ? j : j + 3)] = fcw[(size_t)c * (TT * HH) + t * HH + j];
    }

    int bidx = tid & 15;
    int q = (tid >> 4) & 1;
    int p = tid >> 5;
    int b = blockIdx.x * 16 + bidx;
    int jb = p * HF;   // row base
    int kb = q * HF;   // k base
    bool own_half = (q == p);

    // per-thread weight quarters
    float w0[HF][HF];                 // Whh0[jb+jj][kb+kk]
    float wi1[HF][HF], wh1[HF][HF];   // Wih1 / Whh1 quarters
    float wi2[HF][HF], wh2[HF][HF];
    float bs1[HF], bs2[HF];           // biases only in q==0 lanes
#pragma unroll
    for (int jj = 0; jj < HF; jj++) {
        int j = jb + jj;
#pragma unroll
        for (int kk = 0; kk < HF; kk++) {
            int k = kb + kk;
            w0[jj][kk]  = Whh0[j * HH + k];
            wi1[jj][kk] = Wih1[j * HH + k];
            wh1[jj][kk] = Whh1[j * HH + k];
            wi2[jj][kk] = Wih2[j * HH + k];
            wh2[jj][kk] = Whh2[j * HH + k];
        }
        bs1[jj] = q ? 0.0f : (bih1[j] + bhh1[j]);
        bs2[jj] = q ? 0.0f : (bih2[j] + bhh2[j]);
    }

    // hXq[kk] = h_layerX[q*5+kk] (the k-half this thread consumes)
    float h0q[HF], h1q[HF], h2q[HF];
#pragma unroll
    for (int kk = 0; kk < HF; kk++) {
        h0q[kk] = h0all[(size_t)0 * BB * HH + (size_t)b * HH + kb + kk];
        h1q[kk] = h0all[(size_t)1 * BB * HH + (size_t)b * HH + kb + kk];
        h2q[kk] = h0all[(size_t)2 * BB * HH + (size_t)b * HH + kb + kk];
    }

    float acc[CC];
#pragma unroll
    for (int c = 0; c < CC; c++) acc[c] = 0.0f;

    float pc[HF];
#pragma unroll
    for (int jj = 0; jj < HF; jj++) pc[jj] = P[((size_t)0 * HH + jb + jj) * BB + b];

    __syncthreads();

#pragma unroll 1
    for (int t = 0; t < TT; t++) {
        // prefetch next step's P rows (consumed at loop bottom)
        float pn[HF];
        if (t + 1 < TT) {
#pragma unroll
            for (int jj = 0; jj < HF; jj++)
                pn[jj] = P[((size_t)(t + 1) * HH + jb + jj) * BB + b];
        }
        // prefetch this step's FC weights from LDS (consumed at loop bottom)
        float4 fc4[CC];
        float  fc1[CC];
#pragma unroll
        for (int c = 0; c < CC; c++) {
            const float* base = &sfc[(t * CC + c) * 16 + p * 8];
            fc4[c] = *(const float4*)base;
            fc1[c] = base[4];
        }

        float a[HF], mine[HF];
        // ---- layer 0: a = pc + Whh0(q-half) . h0q ----
#pragma unroll
        for (int jj = 0; jj < HF; jj++) {
            a[jj] = q ? 0.0f : pc[jj];
#pragma unroll
            for (int kk = 0; kk < HF; kk++) a[jj] = fmaf(w0[jj][kk], h0q[kk], a[jj]);
        }
#pragma unroll
        for (int jj = 0; jj < HF; jj++) {           // q-reduce + tanh
            float u = a[jj], v = a[jj];
            swap16(u, v);
            mine[jj] = fast_tanh(u + v);
        }
#pragma unroll
        for (int jj = 0; jj < HF; jj++) {           // p-exchange (orientation-immune)
            float u = mine[jj], v = mine[jj];
            swap32(u, v);
            float s = u + v;
            h0q[jj] = own_half ? mine[jj] : (s - mine[jj]);
        }
        // ---- layer 1: a = bs1 + Wih1(q-half).h0q + Whh1(q-half).h1q ----
#pragma unroll
        for (int jj = 0; jj < HF; jj++) {
            a[jj] = bs1[jj];
#pragma unroll
            for (int kk = 0; kk < HF; kk++) a[jj] = fmaf(wi1[jj][kk], h0q[kk], a[jj]);
#pragma unroll
            for (int kk = 0; kk < HF; kk++) a[jj] = fmaf(wh1[jj][kk], h1q[kk], a[jj]);
        }
#pragma unroll
        for (int jj = 0; jj < HF; jj++) {
            float u = a[jj], v = a[jj];
            swap16(u, v);
            mine[jj] = fast_tanh(u + v);
        }
#pragma unroll
        for (int jj = 0; jj < HF; jj++) {
            float u = mine[jj], v = mine[jj];
            swap32(u, v);
            float s = u + v;
            h1q[jj] = own_half ? mine[jj] : (s - mine[jj]);
        }
        // ---- layer 2 ----
#pragma unroll
        for (int jj = 0; jj < HF; jj++) {
            a[jj] = bs2[jj];
#pragma unroll
            for (int kk = 0; kk < HF; kk++) a[jj] = fmaf(wi2[jj][kk], h1q[kk], a[jj]);
#pragma unroll
            for (int kk = 0; kk < HF; kk++) a[jj] = fmaf(wh2[jj][kk], h2q[kk], a[jj]);
        }
#pragma unroll
        for (int jj = 0; jj < HF; jj++) {
            float u = a[jj], v = a[jj];
            swap16(u, v);
            mine[jj] = fast_tanh(u + v);   // mine = h2 rows jb..jb+4 (this step)
        }
#pragma unroll
        for (int jj = 0; jj < HF; jj++) {
            float u = mine[jj], v = mine[jj];
            swap32(u, v);
            float s = u + v;
            h2q[jj] = own_half ? mine[jj] : (s - mine[jj]);
        }
        // ---- FC partial on own p-half rows (both q redundant) ----
        float r[HF];
#pragma unroll
        for (int jj = 0; jj < HF; jj++) r[jj] = fmaxf(mine[jj], 0.0f);
#pragma unroll
        for (int c = 0; c < CC; c++) {
            acc[c] = fmaf(fc4[c].x, r[0], acc[c]);
            acc[c] = fmaf(fc4[c].y, r[1], acc[c]);
            acc[c] = fmaf(fc4[c].z, r[2], acc[c]);
            acc[c] = fmaf(fc4[c].w, r[3], acc[c]);
            acc[c] = fmaf(fc1[c],  r[4], acc[c]);
        }
#pragma unroll
        for (int jj = 0; jj < HF; jj++) pc[jj] = pn[jj];
    }

    // reduce acc across p (commutative sum, orientation-immune); write from lanes 0-15
    float o[CC];
#pragma unroll
    for (int c = 0; c < CC; c++) {
        float u = acc[c], v = acc[c];
        swap32(u, v);
        o[c] = u + v + fcb[c];
    }
    if (tid < 16) {
#pragma unroll
        for (int c = 0; c < CC; c++) out[(size_t)b * CC + c] = o[c];
    }
}

extern "C" void kernel_launch(void* const* d_in, const int* in_sizes, int n_in,
                              void* d_out, int out_size, void* d_ws, size_t ws_size,
                              hipStream_t stream) {
    const float* x    = (const float*)d_in[0];
    const float* h0   = (const float*)d_in[1];
    const float* Wih0 = (const float*)d_in[2];
    const float* Whh0 = (const float*)d_in[3];
    const float* bih0 = (const float*)d_in[4];
    const float* bhh0 = (const float*)d_in[5];
    const float* Wih1 = (const float*)d_in[6];
    const float* Whh1 = (const float*)d_in[7];
    const float* bih1 = (const float*)d_in[8];
    const float* bhh1 = (const float*)d_in[9];
    const float* Wih2 = (const float*)d_in[10];
    const float* Whh2 = (const float*)d_in[11];
    const float* bih2 = (const float*)d_in[12];
    const float* bhh2 = (const float*)d_in[13];
    const float* fcw  = (const float*)d_in[14];
    const float* fcb  = (const float*)d_in[15];
    float* out = (float*)d_out;
    float* P   = (float*)d_ws;   // [T][H][B] = 16.38 MB

    k_proj0<<<(BB * TT) / 256, 256, 0, stream>>>(x, Wih0, bih0, bhh0, P);
    k_fused<<<BB / 16, 64, 0, stream>>>(h0, Whh0, Wih1, Whh1, bih1, bhh1,
                                        Wih2, Whh2, bih2, bhh2, fcw, fcb, P, out);
}